// Round 1
// 325.241 us; speedup vs baseline: 1.0481x; 1.0481x over previous
//
#include <hip/hip_runtime.h>
#include <hip/hip_fp16.h>
#include <math.h>

#define N_NODES 50000
#define N_EDGES 800000
#define D 128
#define L 3
#define SLOPE 0.2f
#define LN_EPS 1e-5f
#define ETOT (N_EDGES + N_NODES)
#define SCAN_BLOCKS ((N_NODES + 1023) / 1024)   // 49

typedef _Float16 half8 __attribute__((ext_vector_type(8)));
typedef _Float16 h4v  __attribute__((ext_vector_type(4)));
typedef _Float16 h2v  __attribute__((ext_vector_type(2)));
typedef float f32x4 __attribute__((ext_vector_type(4)));

// ---------------- CSR build (once per call, reused for all layers) ----------

__global__ void rank_hist_kernel(const int* __restrict__ ei, int* __restrict__ counts,
                                 int* __restrict__ rank) {
    int idx = blockIdx.x * blockDim.x + threadIdx.x;
    if (idx >= ETOT) return;
    int d = (idx < N_EDGES) ? ei[N_EDGES + idx] : (idx - N_EDGES);
    rank[idx] = atomicAdd(&counts[d], 1);
}

__global__ __launch_bounds__(1024) void scan1_kernel(const int* __restrict__ counts,
                                                     int* __restrict__ offsets,
                                                     int* __restrict__ bsum) {
    __shared__ int wsum[16];
    int tid = threadIdx.x;
    int lane = tid & 63, w = tid >> 6;
    int i = blockIdx.x * 1024 + tid;
    int v = (i < N_NODES) ? counts[i] : 0;
    int sc = v;
    #pragma unroll
    for (int off = 1; off < 64; off <<= 1) {
        int u = __shfl_up(sc, off);
        if (lane >= off) sc += u;
    }
    if (lane == 63) wsum[w] = sc;
    __syncthreads();
    if (w == 0) {
        int t2 = (lane < 16) ? wsum[lane] : 0;
        #pragma unroll
        for (int off = 1; off < 16; off <<= 1) {
            int u = __shfl_up(t2, off);
            if (lane >= off) t2 += u;
        }
        if (lane < 16) wsum[lane] = t2;
    }
    __syncthreads();
    int wpref = (w == 0) ? 0 : wsum[w - 1];
    if (i < N_NODES) offsets[i] = wpref + sc - v;      // block-local exclusive
    if (tid == 0) bsum[blockIdx.x] = wsum[15];
}

__global__ __launch_bounds__(64) void scan2_kernel(const int* __restrict__ bsum,
                                                   int* __restrict__ bpre) {
    int lane = threadIdx.x;
    int v = (lane < SCAN_BLOCKS) ? bsum[lane] : 0;
    int sc = v;
    #pragma unroll
    for (int off = 1; off < 64; off <<= 1) {
        int u = __shfl_up(sc, off);
        if (lane >= off) sc += u;
    }
    if (lane < SCAN_BLOCKS) bpre[lane] = sc - v;       // exclusive
}

__global__ __launch_bounds__(1024) void scan3_kernel(int* __restrict__ offsets,
                                                     const int* __restrict__ bpre) {
    int i = blockIdx.x * 1024 + threadIdx.x;
    if (i < N_NODES) offsets[i] += bpre[blockIdx.x];
    if (i == 0) offsets[N_NODES] = ETOT;
}

__global__ void scatter_kernel(const int* __restrict__ ei, const int* __restrict__ offsets,
                               const int* __restrict__ rank,
                               unsigned short* __restrict__ sorted16) {
    int idx = blockIdx.x * blockDim.x + threadIdx.x;
    if (idx >= ETOT) return;
    int s, d;
    if (idx < N_EDGES) { s = ei[idx]; d = ei[N_EDGES + idx]; }
    else               { s = d = idx - N_EDGES; }
    sorted16[offsets[d] + rank[idx]] = (unsigned short)s;   // no atomic
}

// ---------------- W -> fp16 MFMA B-fragment precompute ---------------------
// Wfrag[l][y][kt][nt][lane][j]; element = W[kt*32+(lane>>4)*8+j][nt*16+(lane&15)]

__global__ __launch_bounds__(256) void wfrag_kernel(const float* __restrict__ Wl,
                                                    const float* __restrict__ Wr,
                                                    _Float16* __restrict__ Wfrag) {
    int u = blockIdx.x * 256 + threadIdx.x;   // 3*2*4*8*64 = 12288 slots
    if (u >= 3 * 4096) return;
    int lane = u & 63, nt = (u >> 6) & 7, kt = (u >> 9) & 3, y = (u >> 11) & 1, l = u >> 12;
    int r = lane & 15, q = lane >> 4;
    const float* W = (y ? Wr : Wl) + (size_t)l * D * D;
    half8 v;
    #pragma unroll
    for (int j = 0; j < 8; ++j)
        v[j] = (_Float16)W[(kt * 32 + q * 8 + j) * D + nt * 16 + r];
    *(half8*)&Wfrag[(size_t)u * 8] = v;
}

// ---------------- MFMA GEMM: xl,xr (fp16) = h @ {Wl,Wr} --------------------
// block = 4 waves; tile M=64, N=256 (both W in one block -> h staged ONCE).

__global__ __launch_bounds__(256) void gemm_mfma_kernel(
        const float* __restrict__ h, const _Float16* __restrict__ WfragL,
        _Float16* __restrict__ xlh, _Float16* __restrict__ xrh) {
    __shared__ half8 Afrag[1024];   // [mt][kt][lane], 16 KB
    int t = threadIdx.x;
    int row0 = blockIdx.x * 64;
    {
        int kt = t >> 6, q = (t >> 4) & 3, r = t & 15;
        int kc = kt * 4 + q;                  // 8-half chunk index
        #pragma unroll
        for (int i = 0; i < 4; ++i) {
            int row = row0 + i * 16 + r;
            float4 f0 = make_float4(0.f, 0.f, 0.f, 0.f), f1 = f0;
            if (row < N_NODES) {
                const float* p = &h[(size_t)row * D + kc * 8];
                f0 = *(const float4*)p;
                f1 = *(const float4*)(p + 4);
            }
            half8 v;
            v[0] = (_Float16)f0.x; v[1] = (_Float16)f0.y;
            v[2] = (_Float16)f0.z; v[3] = (_Float16)f0.w;
            v[4] = (_Float16)f1.x; v[5] = (_Float16)f1.y;
            v[6] = (_Float16)f1.z; v[7] = (_Float16)f1.w;
            Afrag[i * 256 + t] = v;           // linear lanes: conflict-floor
        }
    }
    __syncthreads();
    int w = t >> 6, lane = t & 63;
    f32x4 acc[16];
    #pragma unroll
    for (int i = 0; i < 16; ++i) acc[i] = (f32x4){0.f, 0.f, 0.f, 0.f};
    #pragma unroll
    for (int kt = 0; kt < 4; ++kt) {
        half8 a = Afrag[(w * 4 + kt) * 64 + lane];
        #pragma unroll
        for (int y = 0; y < 2; ++y) {
            #pragma unroll
            for (int nt = 0; nt < 8; ++nt) {
                half8 b = *(const half8*)&WfragL[(size_t)(((y * 4 + kt) * 8 + nt) * 64 + lane) * 8];
                acc[y * 8 + nt] = __builtin_amdgcn_mfma_f32_16x16x32_f16(a, b, acc[y * 8 + nt], 0, 0, 0);
            }
        }
    }
    int rq = lane >> 4, rc = lane & 15;
    int rbase = row0 + w * 16 + rq * 4;       // C/D: col=lane&15, row=(lane>>4)*4+reg
    #pragma unroll
    for (int y = 0; y < 2; ++y) {
        _Float16* out = y ? xrh : xlh;
        #pragma unroll
        for (int nt = 0; nt < 8; ++nt) {
            #pragma unroll
            for (int reg = 0; reg < 4; ++reg) {
                int row = rbase + reg;
                if (row < N_NODES)
                    out[(size_t)row * D + nt * 16 + rc] = (_Float16)acc[y * 8 + nt][reg];
            }
        }
    }
}

// ---------------- per-node GATv2 + softmax + LN + ELU + residual -----------
// TWO nodes per wave: lanes 0-31 -> node 2*wid, lanes 32-63 -> node 2*wid+1.
// Each lane holds 4 channels {4*hl .. 4*hl+3}; head = hl>>2 (4 lanes/head ->
// quad_perm DPP reduction, never crosses the half-wave boundary).
// Each wave-instruction processes one edge of EACH node (an "edge pair").

__device__ __forceinline__ float quad_reduce4(float p) {
    int t;
    t = __builtin_amdgcn_update_dpp(0, __float_as_int(p), 0xB1, 0xF, 0xF, true);  // quad [1,0,3,2]
    p += __int_as_float(t);
    t = __builtin_amdgcn_update_dpp(0, __float_as_int(p), 0x4E, 0xF, 0xF, true);  // quad [2,3,0,1]
    p += __int_as_float(t);
    return p;
}

__device__ __forceinline__ float logit4(h4v v, h2v xrA, h2v xrB, h2v attA, h2v attB,
                                        h2v slope2) {
    h2v v0; v0[0] = v[0]; v0[1] = v[1];
    h2v v1; v1[0] = v[2]; v1[1] = v[3];
    h2v f0 = v0 + xrA;                                    // v_pk_add_f16
    h2v f1 = v1 + xrB;
    h2v lf0 = __builtin_elementwise_max(f0, f0 * slope2); // v_pk_mul/max_f16
    h2v lf1 = __builtin_elementwise_max(f1, f1 * slope2);
    float p = __builtin_amdgcn_fdot2(lf0, attA, 0.f, false);
    return __builtin_amdgcn_fdot2(lf1, attB, p, false);   // chained v_dot2
}

__global__ __launch_bounds__(256) void gat_node_kernel(
        const _Float16* __restrict__ xlh, const _Float16* __restrict__ xrh,
        const int* __restrict__ offsets, const unsigned short* __restrict__ sorted16,
        const float* __restrict__ att_l, const float* __restrict__ bias_l,
        const float* __restrict__ gamma_l, const float* __restrict__ beta_l,
        const float* __restrict__ hin, float* __restrict__ hout) {
    int wid = (blockIdx.x * blockDim.x + threadIdx.x) >> 6;   // wave id
    if (wid * 2 >= N_NODES) return;
    int lane = threadIdx.x & 63;
    int sub = lane >> 5, hl = lane & 31;       // sub-wave (node select), sub-lane
    int node = wid * 2 + sub;                  // N_NODES even -> always valid
    unsigned laneoff = hl * 8u;                // byte offset of this lane's 4 halves

    h4v xr4 = *(const h4v*)&xrh[(size_t)node * D + hl * 4];
    h2v xrA; xrA[0] = xr4[0]; xrA[1] = xr4[1];
    h2v xrB; xrB[0] = xr4[2]; xrB[1] = xr4[3];
    float4 attf = *(const float4*)&att_l[hl * 4];
    h2v attA, attB, slope2;
    attA[0] = (_Float16)(attf.x * 1.44269504f);   // pre-scale by log2(e)
    attA[1] = (_Float16)(attf.y * 1.44269504f);
    attB[0] = (_Float16)(attf.z * 1.44269504f);
    attB[1] = (_Float16)(attf.w * 1.44269504f);
    slope2[0] = (_Float16)SLOPE;
    slope2[1] = (_Float16)SLOPE;

    int beg = offsets[node], end = offsets[node + 1];
    int deg = end - beg;                                     // uniform per half
    int degA = __builtin_amdgcn_readlane(deg, 0);
    int degB = __builtin_amdgcn_readlane(deg, 32);
    int degMax = degA > degB ? degA : degB;

    float s = 0.f;
    float acc0 = 0.f, acc1 = 0.f, acc2 = 0.f, acc3 = 0.f;
    const char* xlb = (const char*)xlh;

    for (int c0 = 0; c0 < degMax; c0 += 32) {
        int rem = deg - c0;
        int cnt = rem > 32 ? 32 : rem;                       // may be <=0 on short half
        int cl  = cnt > 0 ? (hl < cnt ? hl : cnt - 1) : 0;
        int pos = cnt > 0 ? beg + c0 + cl : 0;               // clamped, always in-bounds
        unsigned off = ((unsigned)sorted16[pos]) << 8;       // fp16 row byte offset
        int jmax = degMax - c0; if (jmax > 32) jmax = 32;
        int j = 0;
        for (; j + 8 <= jmax; j += 8) {
            h4v vs[8];
            #pragma unroll
            for (int k = 0; k < 8; ++k) {
                unsigned oA = __builtin_amdgcn_readlane(off, j + k);
                unsigned oB = __builtin_amdgcn_readlane(off, j + k + 32);
                unsigned o  = (sub ? oB : oA) + laneoff;
                vs[k] = *(const h4v*)(xlb + o);              // dwordx2, 8B/lane
            }
            float ems[8];
            #pragma unroll
            for (int k = 0; k < 8; ++k) {
                float p = logit4(vs[k], xrA, xrB, attA, attB, slope2);
                p = quad_reduce4(p);
                float e = __builtin_amdgcn_exp2f(p);
                ems[k] = (j + k < cnt) ? e : 0.f;            // mask short half
            }
            s += ((ems[0] + ems[1]) + (ems[2] + ems[3])) +
                 ((ems[4] + ems[5]) + (ems[6] + ems[7]));
            #pragma unroll
            for (int k = 0; k < 8; ++k) {
                acc0 = fmaf(ems[k], (float)vs[k][0], acc0);  // v_fma_mix
                acc1 = fmaf(ems[k], (float)vs[k][1], acc1);
                acc2 = fmaf(ems[k], (float)vs[k][2], acc2);
                acc3 = fmaf(ems[k], (float)vs[k][3], acc3);
            }
        }
        for (; j < jmax; ++j) {
            unsigned oA = __builtin_amdgcn_readlane(off, j);
            unsigned oB = __builtin_amdgcn_readlane(off, j + 32);
            unsigned o  = (sub ? oB : oA) + laneoff;
            h4v v = *(const h4v*)(xlb + o);
            float p = logit4(v, xrA, xrB, attA, attB, slope2);
            p = quad_reduce4(p);
            float e = __builtin_amdgcn_exp2f(p);
            float em = (j < cnt) ? e : 0.f;
            s += em;
            acc0 = fmaf(em, (float)v[0], acc0);
            acc1 = fmaf(em, (float)v[1], acc1);
            acc2 = fmaf(em, (float)v[2], acc2);
            acc3 = fmaf(em, (float)v[3], acc3);
        }
    }

    float inv = 1.f / s;                 // every node has >=1 edge (self-loop)
    float4 bia = *(const float4*)&bias_l[hl * 4];
    float o0 = acc0 * inv + bia.x;
    float o1 = acc1 * inv + bia.y;
    float o2 = acc2 * inv + bia.z;
    float o3 = acc3 * inv + bia.w;
    float sum = (o0 + o1) + (o2 + o3);
    float sq  = (o0 * o0 + o1 * o1) + (o2 * o2 + o3 * o3);
    #pragma unroll
    for (int msk = 1; msk < 32; msk <<= 1) {   // stays inside the half-wave
        sum += __shfl_xor(sum, msk);
        sq  += __shfl_xor(sq, msk);
    }
    float mu   = sum * (1.f / 128.f);
    float var  = sq * (1.f / 128.f) - mu * mu;
    float rstd = rsqrtf(var + LN_EPS);
    float4 gam = *(const float4*)&gamma_l[hl * 4];
    float4 bet = *(const float4*)&beta_l[hl * 4];
    float y0 = (o0 - mu) * rstd * gam.x + bet.x;
    float y1 = (o1 - mu) * rstd * gam.y + bet.y;
    float y2 = (o2 - mu) * rstd * gam.z + bet.z;
    float y3 = (o3 - mu) * rstd * gam.w + bet.w;
    y0 = y0 > 0.f ? y0 : __expf(y0) - 1.f;      // ELU (alpha=1)
    y1 = y1 > 0.f ? y1 : __expf(y1) - 1.f;
    y2 = y2 > 0.f ? y2 : __expf(y2) - 1.f;
    y3 = y3 > 0.f ? y3 : __expf(y3) - 1.f;
    size_t di = (size_t)node * D + hl * 4;
    float4 hv = *(const float4*)&hin[di];
    hv.x += y0; hv.y += y1; hv.z += y2; hv.w += y3;
    *(float4*)&hout[di] = hv;
}

// ---------------------------------------------------------------------------

extern "C" void kernel_launch(void* const* d_in, const int* in_sizes, int n_in,
                              void* d_out, int out_size, void* d_ws, size_t ws_size,
                              hipStream_t stream) {
    const float* x     = (const float*)d_in[0];
    const float* Wl    = (const float*)d_in[1];
    const float* Wr    = (const float*)d_in[2];
    const float* att   = (const float*)d_in[3];
    const float* bias  = (const float*)d_in[4];
    const float* gamma = (const float*)d_in[5];
    const float* beta  = (const float*)d_in[6];
    const int*   ei    = (const int*)d_in[7];
    float* h = (float*)d_out;

    char* ws = (char*)d_ws;
    _Float16* xlh = (_Float16*)ws;   ws += (size_t)N_NODES * D * sizeof(_Float16);
    _Float16* xrh = (_Float16*)ws;   ws += (size_t)N_NODES * D * sizeof(_Float16);
    _Float16* Wfrag = (_Float16*)ws; ws += (size_t)3 * 4096 * 8 * sizeof(_Float16);
    int* offsets = (int*)ws;         ws += (size_t)(N_NODES + 4) * sizeof(int);
    int* counts  = (int*)ws;         ws += (size_t)N_NODES * sizeof(int);
    int* bsum    = (int*)ws;         ws += 64 * sizeof(int);
    int* bpre    = (int*)ws;         ws += 64 * sizeof(int);
    int* rank    = (int*)ws;         ws += (size_t)ETOT * sizeof(int);
    unsigned short* sorted16 = (unsigned short*)ws;   // ETOT u16

    // W fragments (all layers) + CSR by dst (shared by all 3 layers)
    wfrag_kernel<<<48, 256, 0, stream>>>(Wl, Wr, Wfrag);
    (void)hipMemsetAsync(counts, 0, (size_t)N_NODES * sizeof(int), stream);
    rank_hist_kernel<<<(ETOT + 255) / 256, 256, 0, stream>>>(ei, counts, rank);
    scan1_kernel<<<SCAN_BLOCKS, 1024, 0, stream>>>(counts, offsets, bsum);
    scan2_kernel<<<1, 64, 0, stream>>>(bsum, bpre);
    scan3_kernel<<<SCAN_BLOCKS, 1024, 0, stream>>>(offsets, bpre);
    scatter_kernel<<<(ETOT + 255) / 256, 256, 0, stream>>>(ei, offsets, rank, sorted16);

    int gat_waves  = (N_NODES + 1) / 2;                       // 2 nodes / wave
    int gat_blocks = (gat_waves * 64 + 255) / 256;            // 6250
    for (int l = 0; l < L; ++l) {
        const float* hin = (l == 0) ? x : h;
        gemm_mfma_kernel<<<(N_NODES + 63) / 64, 256, 0, stream>>>(
            hin, Wfrag + (size_t)l * 4096 * 8, xlh, xrh);
        gat_node_kernel<<<gat_blocks, 256, 0, stream>>>(
            xlh, xrh, offsets, sorted16,
            att + (size_t)l * D, bias + (size_t)l * D,
            gamma + (size_t)l * D, beta + (size_t)l * D, hin, h);
    }
}